// Round 4
// baseline (447.016 us; speedup 1.0000x reference)
//
#include <hip/hip_runtime.h>

// SPA (second-price auction) payment kernel.
// x: (BATCH, 16) fp32. Per row: top-2 (m1, m2). out[j] = (x[j]==m1 ? m2 : m1), clamp >= 0.
// Tie semantics: if >=2 elements equal m1 then m2==m1 -> elementwise form is exact
// (absmax 0 in R1-R3).
//
// R4 structure: R1's proven coalesced 4-lanes-per-row layout, wrapped in a
// persistent grid-stride loop with QPT=4 quads in flight per iteration:
//   - 4 fully-coalesced float4 loads issued back-to-back (4 streams, 4 MiB apart)
//   - compute (top2 + 2 shfl_xor merge rounds per quad)
//   - 4 grouped coalesced float4 stores
// Goal: longer pure-read/pure-write bursts at the memory controller + 4x MLP,
// while keeping VGPR <= ~64 for full occupancy.

typedef float f32x4 __attribute__((ext_vector_type(4)));

__device__ __forceinline__ void top2_quad(f32x4 v, float& m1, float& m2) {
    float a = fmaxf(v.x, v.y), b = fminf(v.x, v.y);
    float c = fmaxf(v.z, v.w), d = fminf(v.z, v.w);
    m1 = fmaxf(a, c);
    m2 = fmaxf(fminf(a, c), fmaxf(b, d));
}

__device__ __forceinline__ void row_top2(float& m1, float& m2) {
    // merge (m1,m2) across the 4 lanes of this row (lanes differ in bits 0..1)
    #pragma unroll
    for (int off = 1; off <= 2; off <<= 1) {
        float o1 = __shfl_xor(m1, off);
        float o2 = __shfl_xor(m2, off);
        float hi = fmaxf(m1, o1);
        float lo = fminf(m1, o1);
        m1 = hi;
        m2 = fmaxf(lo, fmaxf(m2, o2));
    }
}

__device__ __forceinline__ f32x4 payment(f32x4 v, float m1, float m2) {
    f32x4 o;
    o.x = fmaxf((v.x == m1) ? m2 : m1, 0.0f);
    o.y = fmaxf((v.y == m1) ? m2 : m1, 0.0f);
    o.z = fmaxf((v.z == m1) ? m2 : m1, 0.0f);
    o.w = fmaxf((v.w == m1) ? m2 : m1, 0.0f);
    return o;
}

#define QPT 4

__global__ __launch_bounds__(256) void _SpaPayment_88399016886488_kernel(
    const f32x4* __restrict__ x, f32x4* __restrict__ out, int nquads) {
    int tid = blockIdx.x * blockDim.x + threadIdx.x;
    int stride = gridDim.x * blockDim.x;

    int base = tid;
    // main loop: QPT coalesced quads in flight per iteration
    for (; base + (QPT - 1) * stride < nquads; base += QPT * stride) {
        f32x4 v[QPT];
        #pragma unroll
        for (int k = 0; k < QPT; ++k)
            v[k] = x[base + k * stride];

        float m1[QPT], m2[QPT];
        #pragma unroll
        for (int k = 0; k < QPT; ++k)
            top2_quad(v[k], m1[k], m2[k]);
        #pragma unroll
        for (int k = 0; k < QPT; ++k)
            row_top2(m1[k], m2[k]);

        f32x4 o[QPT];
        #pragma unroll
        for (int k = 0; k < QPT; ++k)
            o[k] = payment(v[k], m1[k], m2[k]);
        #pragma unroll
        for (int k = 0; k < QPT; ++k)
            out[base + k * stride] = o[k];
    }
    // tail (not taken for the 4194304x16 shape, kept for generality)
    for (; base < nquads; base += stride) {
        f32x4 v = x[base];
        float m1, m2;
        top2_quad(v, m1, m2);
        row_top2(m1, m2);
        out[base] = payment(v, m1, m2);
    }
}

extern "C" void kernel_launch(void* const* d_in, const int* in_sizes, int n_in,
                              void* d_out, int out_size, void* d_ws, size_t ws_size,
                              hipStream_t stream) {
    const f32x4* x = (const f32x4*)d_in[0];
    f32x4* out = (f32x4*)d_out;
    int n = in_sizes[0];          // 4194304 * 16 elements
    int nquads = n / 4;           // 16777216 float4s
    int block = 256;
    int grid = 4096;              // persistent: 16 blocks/CU-worth of waves,
                                  // 16 quads/thread = 4 iterations of QPT=4 (exact)
    _SpaPayment_88399016886488_kernel<<<grid, block, 0, stream>>>(x, out, nquads);
}